// Round 7
// baseline (725.242 us; speedup 1.0000x reference)
//
#include <hip/hip_runtime.h>

typedef unsigned short ushort_t;
typedef unsigned int uint_t;
typedef __attribute__((ext_vector_type(8))) short s8v;     // 8 x bf16 (4 VGPRs)
typedef __attribute__((ext_vector_type(4))) float f4v;     // 4 x fp32

// Problem constants (fixed by the reference)
#define NS0 100000
#define ND0 20000
#define ND1 4000
#define E0  640000
#define E1  128000
#define F   512     // IN_F == HID_F
#define OF  256
#define NCNT (NS0 + ND0 + ND0 + ND1)   // 144000
#define SB  96                          // bucket stride; Poisson(32) max deg ~57, P(>96)~1e-16

#define WBLK ((F * F + F * OF) / 256)      // 1536

__device__ __forceinline__ ushort_t f2b(float f) {
    uint_t u = __float_as_uint(f);
    uint_t r = (u + 0x7fffu + ((u >> 16) & 1u)) >> 16;
    return (ushort_t)r;
}
__device__ __forceinline__ float b2f_lo(uint_t u) { return __uint_as_float(u << 16); }
__device__ __forceinline__ float b2f_hi(uint_t u) { return __uint_as_float(u & 0xffff0000u); }
// packed f32x2 -> bf16x2, RNE (same rounding as f2b). No builtin on gfx950 (m240) — inline asm.
__device__ __forceinline__ uint_t cvtpk(float lo, float hi) {
    uint_t r;
    asm("v_cvt_pk_bf16_f32 %0, %1, %2" : "=v"(r) : "v"(lo), "v"(hi));
    return r;
}
typedef union { s8v v; uint4 u; } s8u;

// Front kernel: bucket-fill (blocks [0,750)) + W transpose-convert.
__global__ __launch_bounds__(256) void prep(const int* __restrict__ src0, const int* __restrict__ dst0,
                                            const int* __restrict__ src1, const int* __restrict__ dst1,
                                            int* __restrict__ cntOut0, int* __restrict__ cntIn0,
                                            int* __restrict__ cntOut1, int* __restrict__ cntIn1,
                                            int* __restrict__ es0, int* __restrict__ es1,
                                            const float* __restrict__ W1, const float* __restrict__ W2,
                                            ushort_t* __restrict__ wt1, ushort_t* __restrict__ wt2) {
    int b = blockIdx.x;
    if (b < 625) {
        int e = (b * 256 + threadIdx.x) * 4;
        int4 s = *(const int4*)(src0 + e);
        int4 d = *(const int4*)(dst0 + e);
        atomicAdd(&cntOut0[s.x], 1);
        atomicAdd(&cntOut0[s.y], 1);
        atomicAdd(&cntOut0[s.z], 1);
        atomicAdd(&cntOut0[s.w], 1);
        int p0 = atomicAdd(&cntIn0[d.x], 1);
        int p1 = atomicAdd(&cntIn0[d.y], 1);
        int p2 = atomicAdd(&cntIn0[d.z], 1);
        int p3 = atomicAdd(&cntIn0[d.w], 1);
        es0[d.x * SB + min(p0, SB - 1)] = s.x;
        es0[d.y * SB + min(p1, SB - 1)] = s.y;
        es0[d.z * SB + min(p2, SB - 1)] = s.z;
        es0[d.w * SB + min(p3, SB - 1)] = s.w;
        return;
    }
    if (b < 750) {
        int e = ((b - 625) * 256 + threadIdx.x) * 4;
        int4 s = *(const int4*)(src1 + e);
        int4 d = *(const int4*)(dst1 + e);
        atomicAdd(&cntOut1[s.x], 1);
        atomicAdd(&cntOut1[s.y], 1);
        atomicAdd(&cntOut1[s.z], 1);
        atomicAdd(&cntOut1[s.w], 1);
        int p0 = atomicAdd(&cntIn1[d.x], 1);
        int p1 = atomicAdd(&cntIn1[d.y], 1);
        int p2 = atomicAdd(&cntIn1[d.z], 1);
        int p3 = atomicAdd(&cntIn1[d.w], 1);
        es1[d.x * SB + min(p0, SB - 1)] = s.x;
        es1[d.y * SB + min(p1, SB - 1)] = s.y;
        es1[d.z * SB + min(p2, SB - 1)] = s.z;
        es1[d.w * SB + min(p3, SB - 1)] = s.w;
        return;
    }
    int i = (b - 750) * 256 + threadIdx.x;
    if (i < F * F) {
        int k = i >> 9, n = i & (F - 1);
        wt1[n * F + k] = f2b(W1[i]);
    } else {
        int j = i - F * F;
        int k = j >> 8, n = j & (OF - 1);
        wt2[n * F + k] = f2b(W2[j]);
    }
}

// gemmA<AF32>: Y[M,N] = bf16( (A @ BT^T) * (rowCnt ? rsqrt(rowCnt[row]) : 1) )
// R6 post-mortem rewrite: gemm_xw was MfmaUtil 11% / 19.2M bank conflicts —
// A-staging (f2b VALU torrent + conflicted ds_write/ds_read) serialized vs MFMA.
// Now: A NEVER touches LDS. Each lane loads its MFMA A-fragment directly from
// global (AF32: 2 x f4v NT + v_cvt_pk_bf16_f32 in-register; bf16: one 16B load).
// Redundant A reads (2 wn-waves x 4 N-blocks) are absorbed by L1/L2 (R6 showed
// FETCH 150MB < 205MB: cache absorption works). B double-buffered in LDS with
// ONE __syncthreads per K-step (minimal 2-phase: stage B(t+1) -> compute(t) ->
// barrier; the vmcnt drain lands after the MFMA phase so B latency hides).
template <bool AF32>
__global__ __launch_bounds__(256) void gemmA(const void* __restrict__ Ap, const ushort_t* __restrict__ BT,
                                             const int* __restrict__ rowCnt, ushort_t* __restrict__ Y,
                                             int M, int N, int K) {
    __shared__ __align__(16) ushort_t Bs[2 * 128 * 64];
    int tid = threadIdx.x;
    int lane = tid & 63, w = tid >> 6;
    int m16 = lane & 15, quad = lane >> 4;
    int wm = w & 1, wn = w >> 1;
    // bijective XCD swizzle (m204): N-tiles sharing an A-panel -> same XCD chunk
    int nwg = (int)gridDim.x;
    int q = nwg >> 3, r = nwg & 7;
    int xcd = (int)blockIdx.x & 7, jj = (int)blockIdx.x >> 3;
    int wg = (xcd < r ? xcd * (q + 1) : r * (q + 1) + (xcd - r) * q) + jj;
    int ntiles = N >> 7;
    int nt = wg % ntiles, mt = wg / ntiles;
    int bm = mt * 128, bn = nt * 128;
    f4v acc[4][4] = {};

    auto stage = [&](int t, int buf) {
        #pragma unroll
        for (int i2 = 0; i2 < 4; ++i2) {
            int c2 = i2 * 256 + tid;
            int row = c2 >> 3, seg = (c2 & 7) * 8;
            __builtin_amdgcn_global_load_lds(
                (const __attribute__((address_space(1))) uint_t*)(BT + (size_t)(bn + row) * K + t * 64 + seg),
                (__attribute__((address_space(3))) uint_t*)(Bs + buf * 8192 + (size_t)c2 * 8), 16, 0, 0);
        }
    };

    int nk = K >> 6;
    int cur = 0;
    stage(0, 0);
    __syncthreads();
    for (int t = 0; t < nk; ++t) {
        if (t + 1 < nk) stage(t + 1, cur ^ 1);
        int k0 = t * 64;
        const ushort_t* bsc = Bs + cur * 8192;
        s8v af0[4], af1[4];
        if constexpr (AF32) {
            const float* A = (const float*)Ap;
            f4v aL0[4], aH0[4], aL1[4], aH1[4];
            #pragma unroll
            for (int m = 0; m < 4; ++m) {
                int ra = bm + wm * 64 + m * 16 + m16; if (ra >= M) ra = M - 1;
                const f4v* ap = (const f4v*)(A + (size_t)ra * K + k0 + quad * 8);
                aL0[m] = __builtin_nontemporal_load(ap);
                aH0[m] = __builtin_nontemporal_load(ap + 1);
                aL1[m] = __builtin_nontemporal_load(ap + 8);     // kc=1: +32 floats
                aH1[m] = __builtin_nontemporal_load(ap + 9);
            }
            #pragma unroll
            for (int m = 0; m < 4; ++m) {
                s8u t0, t1;
                t0.u.x = cvtpk(aL0[m].x, aL0[m].y);
                t0.u.y = cvtpk(aL0[m].z, aL0[m].w);
                t0.u.z = cvtpk(aH0[m].x, aH0[m].y);
                t0.u.w = cvtpk(aH0[m].z, aH0[m].w);
                af0[m] = t0.v;
                t1.u.x = cvtpk(aL1[m].x, aL1[m].y);
                t1.u.y = cvtpk(aL1[m].z, aL1[m].w);
                t1.u.z = cvtpk(aH1[m].x, aH1[m].y);
                t1.u.w = cvtpk(aH1[m].z, aH1[m].w);
                af1[m] = t1.v;
            }
        } else {
            const ushort_t* A = (const ushort_t*)Ap;
            #pragma unroll
            for (int m = 0; m < 4; ++m) {
                int ra = bm + wm * 64 + m * 16 + m16; if (ra >= M) ra = M - 1;
                const ushort_t* ap = A + (size_t)ra * K + k0 + quad * 8;
                af0[m] = *(const s8v*)ap;
                af1[m] = *(const s8v*)(ap + 32);
            }
        }
        #pragma unroll
        for (int kc = 0; kc < 2; ++kc) {
            int co = kc * 32 + quad * 8;
            s8v bf[4];
            #pragma unroll
            for (int nn = 0; nn < 4; ++nn)
                bf[nn] = *(const s8v*)&bsc[(wn * 64 + nn * 16 + m16) * 64 + co];
            #pragma unroll
            for (int m = 0; m < 4; ++m) {
                s8v a = (kc == 0) ? af0[m] : af1[m];
                #pragma unroll
                for (int nn = 0; nn < 4; ++nn)
                    acc[m][nn] = __builtin_amdgcn_mfma_f32_16x16x32_bf16(a, bf[nn], acc[m][nn], 0, 0, 0);
            }
        }
        __syncthreads();
        cur ^= 1;
    }
    #pragma unroll
    for (int m = 0; m < 4; ++m) {
        #pragma unroll
        for (int rr = 0; rr < 4; ++rr) {
            int row = bm + wm * 64 + m * 16 + quad * 4 + rr;
            if (row < M) {
                float rs = rowCnt ? rsqrtf(fmaxf((float)rowCnt[row], 1.0f)) : 1.0f;
                #pragma unroll
                for (int nn = 0; nn < 4; ++nn) {
                    int col = bn + wn * 64 + nn * 16 + m16;
                    Y[(size_t)row * N + col] = f2b(acc[m][nn][rr] * rs);
                }
            }
        }
    }
}

__device__ __forceinline__ void add8(float* acc, uint4 u) {
    acc[0] += b2f_lo(u.x); acc[1] += b2f_hi(u.x);
    acc[2] += b2f_lo(u.y); acc[3] += b2f_hi(u.y);
    acc[4] += b2f_lo(u.z); acc[5] += b2f_hi(u.z);
    acc[6] += b2f_lo(u.w); acc[7] += b2f_hi(u.w);
}

// agg1: h'[d] = rsqrt(outdeg1[d]) * relu( rsqrt(indeg0[d]) * sum_src y[src] + b1 )
// 1KB bf16 row gather; statically-named 2-bank ping/pong pipeline (rule #20).
__global__ __launch_bounds__(256) void agg1(const ushort_t* __restrict__ Yb, const int* __restrict__ es,
                                            const int* __restrict__ cntIn, const int* __restrict__ cntOut1,
                                            const float* __restrict__ b1, ushort_t* __restrict__ out, int ndst) {
    int d = __builtin_amdgcn_readfirstlane(blockIdx.x * 4 + (threadIdx.x >> 6));
    if (d >= ndst) return;
    int lane = threadIdx.x & 63;
    int cntd = cntIn[d];
    int n = min(cntd, SB);
    const int* ed = es + (size_t)d * SB;
    const uint4* Xv = (const uint4*)Yb;
    float acc[8] = {0.f, 0.f, 0.f, 0.f, 0.f, 0.f, 0.f, 0.f};
    int c = n >> 3;
    int i = c << 3;
    if (c > 0) {
        int idP[8], idQ[8];
        uint4 uP[8], uQ[8];
        #pragma unroll
        for (int j = 0; j < 8; ++j) idP[j] = ed[j];
        #pragma unroll
        for (int j = 0; j < 8; ++j) uP[j] = Xv[(size_t)idP[j] * 64 + lane];
        if (c > 1) {
            #pragma unroll
            for (int j = 0; j < 8; ++j) idQ[j] = ed[8 + j];
        }
        int k = 0;
        while (true) {
            if (k + 1 < c) {
                #pragma unroll
                for (int j = 0; j < 8; ++j) uQ[j] = Xv[(size_t)idQ[j] * 64 + lane];
                if (k + 2 < c) {
                    #pragma unroll
                    for (int j = 0; j < 8; ++j) idP[j] = ed[(k + 2) * 8 + j];
                }
            }
            #pragma unroll
            for (int j = 0; j < 8; ++j) add8(acc, uP[j]);
            ++k;
            if (k >= c) break;
            if (k + 1 < c) {
                #pragma unroll
                for (int j = 0; j < 8; ++j) uP[j] = Xv[(size_t)idP[j] * 64 + lane];
                if (k + 2 < c) {
                    #pragma unroll
                    for (int j = 0; j < 8; ++j) idQ[j] = ed[(k + 2) * 8 + j];
                }
            }
            #pragma unroll
            for (int j = 0; j < 8; ++j) add8(acc, uQ[j]);
            ++k;
            if (k >= c) break;
        }
    }
    for (; i < n; ++i) add8(acc, Xv[(size_t)ed[i] * 64 + lane]);
    float rsIn = rsqrtf(fmaxf((float)cntd, 1.0f));
    float rsO1 = rsqrtf(fmaxf((float)cntOut1[d], 1.0f));
    const f4v* bb = (const f4v*)(b1 + lane * 8);
    f4v bA = bb[0], bB = bb[1];
    float v0 = fmaxf(acc[0] * rsIn + bA.x, 0.f) * rsO1;
    float v1 = fmaxf(acc[1] * rsIn + bA.y, 0.f) * rsO1;
    float v2 = fmaxf(acc[2] * rsIn + bA.z, 0.f) * rsO1;
    float v3 = fmaxf(acc[3] * rsIn + bA.w, 0.f) * rsO1;
    float v4 = fmaxf(acc[4] * rsIn + bB.x, 0.f) * rsO1;
    float v5 = fmaxf(acc[5] * rsIn + bB.y, 0.f) * rsO1;
    float v6 = fmaxf(acc[6] * rsIn + bB.z, 0.f) * rsO1;
    float v7 = fmaxf(acc[7] * rsIn + bB.w, 0.f) * rsO1;
    uint4 o;
    o.x = (uint_t)f2b(v0) | ((uint_t)f2b(v1) << 16);
    o.y = (uint_t)f2b(v2) | ((uint_t)f2b(v3) << 16);
    o.z = (uint_t)f2b(v4) | ((uint_t)f2b(v5) << 16);
    o.w = (uint_t)f2b(v6) | ((uint_t)f2b(v7) << 16);
    ((uint4*)out)[(size_t)d * 64 + lane] = o;
}

// agg2: out[d] = relu( rsqrt(indeg1[d]) * sum_src z[src] + b2 )  f32 output.
__global__ __launch_bounds__(256) void agg2(const ushort_t* __restrict__ Z, const int* __restrict__ es,
                                            const int* __restrict__ cntIn, const float* __restrict__ b2,
                                            float* __restrict__ out, int ndst) {
    int d = __builtin_amdgcn_readfirstlane(blockIdx.x * 4 + (threadIdx.x >> 6));
    if (d >= ndst) return;
    int lane = threadIdx.x & 63;
    int cntd = cntIn[d];
    int n = min(cntd, SB);
    const int* ed = es + (size_t)d * SB;
    const uint2* Zv = (const uint2*)Z;
    float a0 = 0.f, a1 = 0.f, a2 = 0.f, a3 = 0.f;
    int c = n >> 3;
    int i = c << 3;
    if (c > 0) {
        int idP[8], idQ[8];
        uint2 uP[8], uQ[8];
        #pragma unroll
        for (int j = 0; j < 8; ++j) idP[j] = ed[j];
        #pragma unroll
        for (int j = 0; j < 8; ++j) uP[j] = Zv[(size_t)idP[j] * 64 + lane];
        if (c > 1) {
            #pragma unroll
            for (int j = 0; j < 8; ++j) idQ[j] = ed[8 + j];
        }
        int k = 0;
        while (true) {
            if (k + 1 < c) {
                #pragma unroll
                for (int j = 0; j < 8; ++j) uQ[j] = Zv[(size_t)idQ[j] * 64 + lane];
                if (k + 2 < c) {
                    #pragma unroll
                    for (int j = 0; j < 8; ++j) idP[j] = ed[(k + 2) * 8 + j];
                }
            }
            #pragma unroll
            for (int j = 0; j < 8; ++j) {
                a0 += b2f_lo(uP[j].x); a1 += b2f_hi(uP[j].x);
                a2 += b2f_lo(uP[j].y); a3 += b2f_hi(uP[j].y);
            }
            ++k;
            if (k >= c) break;
            if (k + 1 < c) {
                #pragma unroll
                for (int j = 0; j < 8; ++j) uP[j] = Zv[(size_t)idP[j] * 64 + lane];
                if (k + 2 < c) {
                    #pragma unroll
                    for (int j = 0; j < 8; ++j) idQ[j] = ed[(k + 2) * 8 + j];
                }
            }
            #pragma unroll
            for (int j = 0; j < 8; ++j) {
                a0 += b2f_lo(uQ[j].x); a1 += b2f_hi(uQ[j].x);
                a2 += b2f_lo(uQ[j].y); a3 += b2f_hi(uQ[j].y);
            }
            ++k;
            if (k >= c) break;
        }
    }
    for (; i < n; ++i) {
        uint2 u = Zv[(size_t)ed[i] * 64 + lane];
        a0 += b2f_lo(u.x); a1 += b2f_hi(u.x);
        a2 += b2f_lo(u.y); a3 += b2f_hi(u.y);
    }
    float rs = rsqrtf(fmaxf((float)cntd, 1.0f));
    f4v bb = *(const f4v*)(b2 + lane * 4);
    f4v o;
    o.x = fmaxf(a0 * rs + bb.x, 0.f);
    o.y = fmaxf(a1 * rs + bb.y, 0.f);
    o.z = fmaxf(a2 * rs + bb.z, 0.f);
    o.w = fmaxf(a3 * rs + bb.w, 0.f);
    ((f4v*)out)[(size_t)d * 64 + lane] = o;
}

extern "C" void kernel_launch(void* const* d_in, const int* in_sizes, int n_in,
                              void* d_out, int out_size, void* d_ws, size_t ws_size,
                              hipStream_t stream) {
    (void)in_sizes; (void)n_in; (void)out_size; (void)ws_size;
    const float* x    = (const float*)d_in[0];
    const int*   src0 = (const int*)d_in[1];
    const int*   dst0 = (const int*)d_in[2];
    const int*   src1 = (const int*)d_in[3];
    const int*   dst1 = (const int*)d_in[4];
    const float* W1   = (const float*)d_in[5];
    const float* b1   = (const float*)d_in[6];
    const float* W2   = (const float*)d_in[7];
    const float* b2   = (const float*)d_in[8];
    float* out = (float*)d_out;

    char* p = (char*)d_ws;
    auto alloc = [&](size_t bytes) { char* q = p; p += (bytes + 255) & ~(size_t)255; return q; };
    int*      cnt  = (int*)alloc((size_t)NCNT * 4);
    int*      es0  = (int*)alloc((size_t)ND0 * SB * 4);
    int*      es1  = (int*)alloc((size_t)ND1 * SB * 4);
    ushort_t* wt1  = (ushort_t*)alloc((size_t)F * F * 2);
    ushort_t* wt2  = (ushort_t*)alloc((size_t)OF * F * 2);
    ushort_t* y    = (ushort_t*)alloc((size_t)NS0 * F * 2);    // x @ W1, outdeg0-prescaled
    ushort_t* hp   = (ushort_t*)alloc((size_t)ND0 * F * 2);    // layer-1 out, outdeg1-prescaled
    ushort_t* z    = (ushort_t*)alloc((size_t)ND0 * OF * 2);   // hp @ W2

    int* cntOut0 = cnt;                      // [NS0]
    int* cntIn0  = cnt + NS0;                // [ND0]
    int* cntOut1 = cnt + NS0 + ND0;          // [ND0]
    int* cntIn1  = cnt + NS0 + ND0 + ND0;    // [ND1]

    (void)hipMemsetAsync(cnt, 0, (size_t)NCNT * 4, stream);

    prep<<<750 + WBLK, 256, 0, stream>>>(src0, dst0, src1, dst1,
                                         cntOut0, cntIn0, cntOut1, cntIn1, es0, es1,
                                         W1, W2, wt1, wt2);

    // y = (x @ W1) * outdeg0^-1/2 ; grid = 782 M-tiles * 4 N-tiles
    gemmA<true><<<3128, 256, 0, stream>>>(x, wt1, cntOut0, y, NS0, F, F);

    agg1<<<(ND0 + 3) / 4, 256, 0, stream>>>(y, es0, cntIn0, cntOut1, b1, hp, ND0);

    // z = hp @ W2 ; 157 M-tiles * 2 N-tiles
    gemmA<false><<<314, 256, 0, stream>>>(hp, wt2, nullptr, z, ND0, OF, F);

    agg2<<<(ND1 + 3) / 4, 256, 0, stream>>>(z, es1, cntIn1, b2, out, ND1);
}